// Round 5
// baseline (672.694 us; speedup 1.0000x reference)
//
#include <hip/hip_runtime.h>

typedef unsigned short u16;
typedef __bf16 bf16x8 __attribute__((ext_vector_type(8)));
typedef u16 u16x8 __attribute__((ext_vector_type(8)));
typedef float floatx4 __attribute__((ext_vector_type(4)));

#define NB 16
#define NC 728
#define HW 38
#define NP 1444        // 38*38
#define NPIX 16819712  // 16*728*1444
#define K2 736         // K padded to 23*32
#define P2 1536        // 1444 padded to 12*128
#define M2 768         // 728 padded to 6*128

__device__ __forceinline__ u16 f2bf(float f) {
  union { float f; unsigned int i; } v; v.f = f;
  unsigned int r = v.i + 0x7FFFu + ((v.i >> 16) & 1u);
  return (u16)(r >> 16);
}

__device__ __forceinline__ void async16(const u16* g, u16* l) {
  __builtin_amdgcn_global_load_lds((__attribute__((address_space(1))) void*)g,
                                   (__attribute__((address_space(3))) void*)l,
                                   16, 0, 0);
}

// ---------- kernel 0: fold dw-conv + BN + gamma gates into per-channel mul/add ----------
__global__ void prep_params(const float* __restrict__ gF, const float* __restrict__ gL,
                            const float* __restrict__ dwfw, const float* __restrict__ dwfb,
                            const float* __restrict__ dwlw, const float* __restrict__ dwlb,
                            const float* __restrict__ fs, const float* __restrict__ fb,
                            const float* __restrict__ fm, const float* __restrict__ fv,
                            const float* __restrict__ ls, const float* __restrict__ lb,
                            const float* __restrict__ lm, const float* __restrict__ lv,
                            float* __restrict__ mulF, float* __restrict__ addF,
                            float* __restrict__ mulL, float* __restrict__ addL) {
  int c = blockIdx.x * 256 + threadIdx.x;
  if (c >= NC) return;
  float gf = 2.f / (1.f + __expf(-gF[0])) - 1.f;   // sigmoid*2-1
  float gl = 2.f / (1.f + __expf(-gL[0])) - 1.f;
  float invf = fs[c] * rsqrtf(fv[c] + 1e-5f);
  mulF[c] = gl * dwfw[c] * invf;                              // multiplies x_LFS*att
  addF[c] = (dwfb[c] - fm[c]) * invf + fb[c];
  float invl = ls[c] * rsqrtf(lv[c] + 1e-5f);
  mulL[c] = gf * dwlw[c] * invl;                              // multiplies x_FAD*att
  addL[c] = (dwlb[c] - lm[c]) * invl + lb[c];
}

// ---------- kernel 1: x fp32 [b][c][p] -> xT bf16 [b_local][p(1536)][c(736)] zero-padded ----------
// Rewritten for store coalescing: 64p x 128c tile; phase-2 writes u16x8 (16B/thread,
// 1KB per wave-instruction). LDS row pad 69 -> phase-2 strided reads ~2-way on banks (free).
// z in [0, 2*ng): first ng = FAD batches, next ng = LFS batches.
__global__ __launch_bounds__(256) void transpose_pad(const float* __restrict__ xF,
                                                     const float* __restrict__ xL,
                                                     u16* __restrict__ xTF,
                                                     u16* __restrict__ xTL,
                                                     int bbase, int ng) {
  __shared__ u16 tile[128][69];
  int z = blockIdx.z;
  int tensor = (z >= ng) ? 1 : 0;
  int bl = z - (tensor ? ng : 0);  // group-local batch
  int b = bbase + bl;              // global batch
  const float* x = tensor ? xL : xF;
  u16* xT = tensor ? xTL : xTF;
  int p0 = blockIdx.x * 64, c0 = blockIdx.y * 128;
  int t = threadIdx.x;
  // phase 1: float4 loads; 16 lanes cover 64 p, 16 c-rows per iter, 8 iters
  int pl4 = (t & 15) * 4, csub = t >> 4;
  bool fullp = (p0 + 63) < NP;
#pragma unroll
  for (int it = 0; it < 8; ++it) {
    int cl = it * 16 + csub;
    int c = c0 + cl, p = p0 + pl4;
    u16 o0v = 0, o1 = 0, o2 = 0, o3 = 0;
    if (c < NC) {
      const float* src = &x[(size_t)(b * NC + c) * NP + p];
      if (fullp) {
        float4 v = *(const float4*)src;
        o0v = f2bf(v.x); o1 = f2bf(v.y); o2 = f2bf(v.z); o3 = f2bf(v.w);
      } else {
        if (p + 0 < NP) o0v = f2bf(src[0]);
        if (p + 1 < NP) o1 = f2bf(src[1]);
        if (p + 2 < NP) o2 = f2bf(src[2]);
        if (p + 3 < NP) o3 = f2bf(src[3]);
      }
    }
    tile[cl][pl4] = o0v; tile[cl][pl4 + 1] = o1; tile[cl][pl4 + 2] = o2; tile[cl][pl4 + 3] = o3;
  }
  __syncthreads();
  // phase 2: write [p][c] with 8 consecutive c per thread (16B stores, coalesced per row)
  int j = t & 15, psub = t >> 4;   // j -> c-group of 8, psub -> p within 16
#pragma unroll
  for (int it = 0; it < 4; ++it) {
    int pl = it * 16 + psub;
    int cg = j * 8;
    int c = c0 + cg;
    if (c < K2) {  // c, K2 multiples of 8 -> full group in-range
      u16x8 v;
#pragma unroll
      for (int k = 0; k < 8; ++k) v[k] = tile[cg + k][pl];
      *(u16x8*)&xT[(size_t)(bl * P2 + p0 + pl) * K2 + c] = v;
    }
  }
}

// ---------- kernel 2: pad + PRE-SWIZZLE 4 weight matrices into MFMA-fragment order ----------
// Layout per combo: element idx = ((og*23 + kt)*64 + lane)*8 + j  where
//   og in [0,48) = 16-row output group, kt = K-step, lane = MFMA lane, j = bf16 within 16B.
//   value = W[og*16 + (lane&15)][kt*32 + (lane>>4)*8 + j]  (zero-padded).
// Each A-fragment (og,kt) is then ONE fully-coalesced 1KB wave load in conv_gemm.
__global__ void pad_weights(const float* __restrict__ W0, const float* __restrict__ W1,
                            const float* __restrict__ W2, const float* __restrict__ W3,
                            u16* __restrict__ Wpad) {
  int combo = blockIdx.y;
  const float* W = combo == 0 ? W0 : combo == 1 ? W1 : combo == 2 ? W2 : W3;
  int idx = blockIdx.x * 256 + threadIdx.x;
  if (idx >= M2 * K2) return;
  int j = idx & 7;
  int l = (idx >> 3) & 63;
  int v = idx >> 9;            // og*23 + kt
  int kt = v % 23, og = v / 23;
  int row = og * 16 + (l & 15);
  int col = kt * 32 + (l >> 4) * 8 + j;
  u16 val = (row < NC && col < NC) ? f2bf(W[row * NC + col]) : (u16)0;
  Wpad[(size_t)combo * (M2 * K2) + idx] = val;
}

// ---------- kernel 3: conv1x1 GEMM  Out[bl][o][p] = sum_c W[o][c]*xT[bl][p][c] + bias[o] ----------
// A (weights) direct from global in fragment order (pre-swizzled; L2-hot), REGISTER-
// PIPELINED one K-step ahead so the L2 latency hides under MFMA+barrier of step kt.
// LDS carries only B (double-buffered, gload_lds width-16, one barrier per K-step).
// grid: (12, 12, 2*ng) = (xc: o-tile x combo-half, p-tile, bl x tensor); nwg % 8 == 0.
__global__ __launch_bounds__(256) void conv_gemm(const u16* __restrict__ Wpad,
                                                 const u16* __restrict__ xTF,
                                                 const u16* __restrict__ xTL,
                                                 const float* __restrict__ b0, const float* __restrict__ b1,
                                                 const float* __restrict__ b2, const float* __restrict__ b3,
                                                 u16* __restrict__ Qf, u16* __restrict__ Kf,
                                                 u16* __restrict__ Ql, u16* __restrict__ Kl) {
  __shared__ __align__(16) u16 B_lds[2][128 * 32];
  int t = threadIdx.x;
  int lane = t & 63, w = t >> 6;

  // XCD chunk swizzle over the flat work id (T1, bijective: nwg multiple of 8)
  unsigned int f = blockIdx.x + 12u * (blockIdx.y + 12u * blockIdx.z);
  unsigned int nwg = 144u * gridDim.z;
  unsigned int q = nwg >> 3;
  unsigned int wid = (f & 7u) * q + (f >> 3);
  unsigned int xc = wid % 12u;
  unsigned int r1 = wid / 12u;
  unsigned int pt = r1 % 12u;
  unsigned int zz = r1 / 12u;
  int bl = (int)(zz >> 1);
  int th = (int)(zz & 1u);                 // 0 = FAD (Q/K f), 1 = LFS
  int combo = th * 2 + (xc >= 6u ? 1 : 0);
  int o0 = (int)(xc % 6u) * 128;
  int p0 = (int)pt * 128;

  const u16* WbS = Wpad + (size_t)combo * (M2 * K2);
  const u16* Xb = (th == 0 ? xTF : xTL) + (size_t)bl * (P2 * K2);
  const float* bias = combo == 0 ? b0 : combo == 1 ? b1 : combo == 2 ? b2 : b3;
  u16* Out = combo == 0 ? Qf : combo == 1 ? Kf : combo == 2 ? Ql : Kl;

  // B async staging: wave w covers 32 rows (2 calls x 16 rows); lane L -> row L/4, chunk L%4
  const u16* Bg = Xb + (size_t)(p0 + w * 32 + (lane >> 2)) * K2 + (lane & 3) * 8;

  floatx4 acc[4][4] = {};
  int wm = w >> 1, wn = w & 1;
  int ln = lane & 15, qd = lane >> 4;
  // A fragment base for this wave: og0 = o0/16 + wm*4; fragment (og0+mt, kt) at
  //   WbS + ((og0+mt)*23 + kt)*512 + lane*8   (u16 units; 512 u16 = 1KB per fragment)
  const u16* Afrag = WbS + (size_t)((o0 >> 4) + wm * 4) * 23 * 512 + (size_t)lane * 8;
  int rdoffB = (wn * 64 + ln) * 32 + qd * 8;

  // prologue: stage B tile 0 into buffer 0; prefetch A fragments for kt=0
  async16(Bg, &B_lds[0][w * 32 * 32]);
  async16(Bg + 16 * K2, &B_lds[0][w * 32 * 32 + 16 * 32]);
  bf16x8 afn[4];
#pragma unroll
  for (int mt = 0; mt < 4; ++mt)
    afn[mt] = *(const bf16x8*)(Afrag + (size_t)(mt * 23) * 512);
  __syncthreads();  // vmcnt(0) drained -> buf0 ready

  int cur = 0;
  for (int kt = 0; kt < 23; ++kt) {
    if (kt + 1 < 23) {  // prefetch B tile kt+1 before compute of tile kt
      int ko = (kt + 1) * 32;
      u16* Bl = &B_lds[cur ^ 1][w * 32 * 32];
      async16(Bg + ko, Bl);
      async16(Bg + ko + 16 * K2, Bl + 16 * 32);
    }
    bf16x8 af[4], bfv[4];
#pragma unroll
    for (int mt = 0; mt < 4; ++mt) af[mt] = afn[mt];
    if (kt + 1 < 23) {  // register-prefetch A fragments for kt+1 (consumed next iter)
#pragma unroll
      for (int mt = 0; mt < 4; ++mt)
        afn[mt] = *(const bf16x8*)(Afrag + (size_t)(mt * 23 + kt + 1) * 512);
    }
#pragma unroll
    for (int nt = 0; nt < 4; ++nt)
      bfv[nt] = *(const bf16x8*)&B_lds[cur][rdoffB + nt * 16 * 32];
#pragma unroll
    for (int mt = 0; mt < 4; ++mt)
#pragma unroll
      for (int nt = 0; nt < 4; ++nt)
        acc[mt][nt] = __builtin_amdgcn_mfma_f32_16x16x32_bf16(af[mt], bfv[nt], acc[mt][nt], 0, 0, 0);
    __syncthreads();  // reads of buf[cur] done everywhere; prefetch into buf[cur^1] drained
    cur ^= 1;
  }

  // epilogue: C/D layout col=lane&15 (p), row=quad*4+reg (o); add bias, store bf16
#pragma unroll
  for (int mt = 0; mt < 4; ++mt)
#pragma unroll
    for (int reg = 0; reg < 4; ++reg) {
      int o_r = o0 + wm * 64 + mt * 16 + qd * 4 + reg;
      if (o_r < NC) {
        float bv = bias[o_r];
#pragma unroll
        for (int nt = 0; nt < 4; ++nt) {
          int p_c = p0 + wn * 64 + nt * 16 + ln;
          if (p_c < NP) Out[(size_t)(bl * NC + o_r) * NP + p_c] = f2bf(acc[mt][nt][reg] + bv);
        }
      }
    }
}

// ---------- kernel 4: per-(bl,c) energy GEMM + softmax + fused output epilogue ----------
// One wave per (b_local,c). E[i,k] = sum_j qf[i,j]kf[k,j] + ql[i,j]kl[k,j]; K-dim padded
// layout [48 rows][96 cols]: cols 0..37 = FAD j, 48..85 = LFS j (pad cols zeroed).
// Rows 38..47 are left as garbage: they feed only E rows/cols that softmax+epilogue mask.
__global__ __launch_bounds__(64) void attn_final(const u16* __restrict__ Qf, const u16* __restrict__ Kf,
                                                 const u16* __restrict__ Ql, const u16* __restrict__ Kl,
                                                 const float* __restrict__ xF, const float* __restrict__ xL,
                                                 const float* __restrict__ mulF, const float* __restrict__ addF,
                                                 const float* __restrict__ mulL, const float* __restrict__ addL,
                                                 float* __restrict__ out, int bbase) {
  __shared__ __align__(16) u16 q_lds[48 * 96];
  __shared__ __align__(16) u16 k_lds[48 * 96];
  int bc = blockIdx.x;                 // bl*NC + c
  int bl = bc / NC, c = bc - bl * NC;
  int t = threadIdx.x;                 // one wave: t == lane
  int base = bc * NP;                  // group-local Q/K base
  int gbase = ((bbase + bl) * NC + c) * NP;  // global x/out base

  // zero contraction-pad cols (38..47, 86..95) for rows 0..37 (u32 = 2 cols per write)
  for (int i = t; i < 38 * 5; i += 64) {
    int r = i / 5, c2 = (i - r * 5) * 2;
    *(unsigned int*)&q_lds[r * 96 + 38 + c2] = 0;
    *(unsigned int*)&q_lds[r * 96 + 86 + c2] = 0;
    *(unsigned int*)&k_lds[r * 96 + 38 + c2] = 0;
    *(unsigned int*)&k_lds[r * 96 + 86 + c2] = 0;
  }

  // vectorized staging: 3 dwordx4 sweeps per array; scatter 8 u16 each into [48][96]
#define STAGE(SRC, DST, COL0)                                              \
  {                                                                        \
    _Pragma("unroll") for (int s = 0; s < 3; ++s) {                        \
      int e0 = (s * 64 + t) * 8;                                           \
      if (e0 < NP) {                                                       \
        u16x8 v = *(const u16x8*)(SRC + base + e0);                        \
        int r = e0 / 38, cc = e0 - r * 38;                                 \
        _Pragma("unroll") for (int j = 0; j < 8; ++j) {                    \
          if (e0 + j < NP) DST[r * 96 + (COL0) + cc] = v[j];               \
          if (++cc == 38) { cc = 0; ++r; }                                 \
        }                                                                  \
      }                                                                    \
    }                                                                      \
  }
  STAGE(Qf, q_lds, 0)
  STAGE(Ql, q_lds, 48)
  STAGE(Kf, k_lds, 0)
  STAGE(Kl, k_lds, 48)
#undef STAGE
  __syncthreads();

  int ln = t & 15, qd = t >> 4;
  floatx4 acc[3][3] = {};
#pragma unroll
  for (int ks = 0; ks < 3; ++ks) {
    bf16x8 af[3], bfv[3];
#pragma unroll
    for (int mt = 0; mt < 3; ++mt) af[mt] = *(const bf16x8*)&q_lds[(mt * 16 + ln) * 96 + ks * 32 + qd * 8];
#pragma unroll
    for (int nt = 0; nt < 3; ++nt) bfv[nt] = *(const bf16x8*)&k_lds[(nt * 16 + ln) * 96 + ks * 32 + qd * 8];
#pragma unroll
    for (int mt = 0; mt < 3; ++mt)
#pragma unroll
      for (int nt = 0; nt < 3; ++nt)
        acc[mt][nt] = __builtin_amdgcn_mfma_f32_16x16x32_bf16(af[mt], bfv[nt], acc[mt][nt], 0, 0, 0);
  }
  // softmax over k (axis -1). Row i lives in lanes sharing quad: reduce width 16.
  float rinv[3][4];
#pragma unroll
  for (int mt = 0; mt < 3; ++mt)
#pragma unroll
    for (int reg = 0; reg < 4; ++reg) {
      float m = -1e30f;
#pragma unroll
      for (int nt = 0; nt < 3; ++nt)
        if (nt * 16 + ln < HW) m = fmaxf(m, acc[mt][nt][reg]);
#pragma unroll
      for (int off = 8; off > 0; off >>= 1) m = fmaxf(m, __shfl_xor(m, off, 16));
      float s = 0.f;
#pragma unroll
      for (int nt = 0; nt < 3; ++nt) {
        float v = (nt * 16 + ln < HW) ? __expf(acc[mt][nt][reg] - m) : 0.f;
        acc[mt][nt][reg] = v;
        s += v;
      }
#pragma unroll
      for (int off = 8; off > 0; off >>= 1) s += __shfl_xor(s, off, 16);
      rinv[mt][reg] = 1.f / s;
    }

  __syncthreads();  // all q_lds fragment reads done; safe to overwrite with probs
  float* att = (float*)q_lds;  // 1444 f32 = 5776 B < 9216 B
#pragma unroll
  for (int mt = 0; mt < 3; ++mt)
#pragma unroll
    for (int reg = 0; reg < 4; ++reg) {
      int i = mt * 16 + qd * 4 + reg;
      if (i < HW) {
#pragma unroll
        for (int nt = 0; nt < 3; ++nt) {
          int k = nt * 16 + ln;
          if (k < HW) att[i * HW + k] = acc[mt][nt][reg] * rinv[mt][reg];
        }
      }
    }
  __syncthreads();

  // coalesced fused epilogue: p-contiguous float4 over both outputs
  float mf = mulF[c], adf = addF[c], ml = mulL[c], adl = addL[c];
#pragma unroll
  for (int s = 0; s < 6; ++s) {
    int p = s * 256 + t * 4;
    if (p < NP) {  // NP % 4 == 0: every in-range float4 is full
      float4 a  = *(const float4*)&att[p];
      float4 xf = *(const float4*)&xF[gbase + p];
      float4 xl = *(const float4*)&xL[gbase + p];
      float4 yf, yl;
      yf.x = fmaf(xl.x * a.x, mf, xf.x + adf); yl.x = fmaf(xf.x * a.x, ml, xl.x + adl);
      yf.y = fmaf(xl.y * a.y, mf, xf.y + adf); yl.y = fmaf(xf.y * a.y, ml, xl.y + adl);
      yf.z = fmaf(xl.z * a.z, mf, xf.z + adf); yl.z = fmaf(xf.z * a.z, ml, xl.z + adl);
      yf.w = fmaf(xl.w * a.w, mf, xf.w + adf); yl.w = fmaf(xf.w * a.w, ml, xl.w + adl);
      *(float4*)&out[gbase + p] = yf;
      *(float4*)&out[NPIX + gbase + p] = yl;
    }
  }
}

extern "C" void kernel_launch(void* const* d_in, const int* in_sizes, int n_in,
                              void* d_out, int out_size, void* d_ws, size_t ws_size,
                              hipStream_t stream) {
  (void)in_sizes; (void)n_in; (void)out_size;
  const float* xF   = (const float*)d_in[0];
  const float* xL   = (const float*)d_in[1];
  const float* Wq_f = (const float*)d_in[2];
  const float* bq_f = (const float*)d_in[3];
  const float* Wq_l = (const float*)d_in[4];
  const float* bq_l = (const float*)d_in[5];
  const float* Wk_f = (const float*)d_in[6];
  const float* bk_f = (const float*)d_in[7];
  const float* Wk_l = (const float*)d_in[8];
  const float* bk_l = (const float*)d_in[9];
  const float* gF   = (const float*)d_in[10];
  const float* gL   = (const float*)d_in[11];
  const float* dwfw = (const float*)d_in[12];
  const float* dwfb = (const float*)d_in[13];
  const float* dwlw = (const float*)d_in[14];
  const float* dwlb = (const float*)d_in[15];
  const float* fs   = (const float*)d_in[16];
  const float* fb   = (const float*)d_in[17];
  const float* fm   = (const float*)d_in[18];
  const float* fv   = (const float*)d_in[19];
  const float* ls   = (const float*)d_in[20];
  const float* lb   = (const float*)d_in[21];
  const float* lm   = (const float*)d_in[22];
  const float* lv   = (const float*)d_in[23];

  // Dynamic group size: single pass (ng=16) needs 211.4 MB of workspace;
  // ng=8 -> 108.0 MB; ng=4 -> 56.3 MB.
  const size_t small_bytes = 4 * (size_t)NC * sizeof(float);
  const size_t wpad_bytes  = (size_t)4 * M2 * K2 * 2;
  const size_t perb_bytes  = (size_t)2 * P2 * K2 * 2
                           + (size_t)4 * NC * NP * 2;
  int ng = 16;
  while (ng > 4 && small_bytes + wpad_bytes + (size_t)ng * perb_bytes > ws_size) ng >>= 1;

  char* ws = (char*)d_ws;
  size_t off = 0;
  float* mulF = (float*)(ws + off); off += NC * sizeof(float);
  float* addF = (float*)(ws + off); off += NC * sizeof(float);
  float* mulL = (float*)(ws + off); off += NC * sizeof(float);
  float* addL = (float*)(ws + off); off += NC * sizeof(float);
  off = (off + 15) & ~(size_t)15;
  u16* Wpad = (u16*)(ws + off); off += wpad_bytes;
  u16* xTF  = (u16*)(ws + off); off += (size_t)ng * P2 * K2 * 2;
  u16* xTL  = (u16*)(ws + off); off += (size_t)ng * P2 * K2 * 2;
  u16* Qf   = (u16*)(ws + off); off += (size_t)ng * NC * NP * 2;
  u16* Kf   = (u16*)(ws + off); off += (size_t)ng * NC * NP * 2;
  u16* Ql   = (u16*)(ws + off); off += (size_t)ng * NC * NP * 2;
  u16* Kl   = (u16*)(ws + off); off += (size_t)ng * NC * NP * 2;

  prep_params<<<dim3(3), dim3(256), 0, stream>>>(gF, gL, dwfw, dwfb, dwlw, dwlb,
                                                 fs, fb, fm, fv, ls, lb, lm, lv,
                                                 mulF, addF, mulL, addL);
  pad_weights<<<dim3((M2 * K2 + 255) / 256, 4), dim3(256), 0, stream>>>(Wq_f, Wk_f, Wq_l, Wk_l, Wpad);
  for (int g = 0; g < NB; g += ng) {
    transpose_pad<<<dim3(P2 / 64, 6, 2 * ng), dim3(256), 0, stream>>>(xF, xL, xTF, xTL, g, ng);
    conv_gemm<<<dim3(12, 12, 2 * ng), dim3(256), 0, stream>>>(Wpad, xTF, xTL,
                                                              bq_f, bk_f, bq_l, bk_l,
                                                              Qf, Kf, Ql, Kl);
    attn_final<<<dim3(ng * NC), dim3(64), 0, stream>>>(Qf, Kf, Ql, Kl, xF, xL,
                                                       mulF, addF, mulL, addL,
                                                       (float*)d_out, g);
  }
}

// Round 6
// 591.363 us; speedup vs baseline: 1.1375x; 1.1375x over previous
//
#include <hip/hip_runtime.h>

typedef unsigned short u16;
typedef __bf16 bf16x8 __attribute__((ext_vector_type(8)));
typedef u16 u16x8 __attribute__((ext_vector_type(8)));
typedef float floatx4 __attribute__((ext_vector_type(4)));

#define NB 16
#define NC 728
#define HW 38
#define NP 1444        // 38*38
#define NPIX 16819712  // 16*728*1444
#define K3 768         // K padded to 12*64 (BK=64; cols 728..767 zero)
#define NKT 24         // 32-wide k-slots (2 per BK step)
#define P2 1536        // 1444 padded to 12*128
#define M2 768         // 728 padded to 6*128

__device__ __forceinline__ u16 f2bf(float f) {
  union { float f; unsigned int i; } v; v.f = f;
  unsigned int r = v.i + 0x7FFFu + ((v.i >> 16) & 1u);
  return (u16)(r >> 16);
}

__device__ __forceinline__ void async16(const u16* g, u16* l) {
  __builtin_amdgcn_global_load_lds((__attribute__((address_space(1))) void*)g,
                                   (__attribute__((address_space(3))) void*)l,
                                   16, 0, 0);
}

// ---------- kernel 0: fold dw-conv + BN + gamma gates into per-channel mul/add ----------
__global__ void prep_params(const float* __restrict__ gF, const float* __restrict__ gL,
                            const float* __restrict__ dwfw, const float* __restrict__ dwfb,
                            const float* __restrict__ dwlw, const float* __restrict__ dwlb,
                            const float* __restrict__ fs, const float* __restrict__ fb,
                            const float* __restrict__ fm, const float* __restrict__ fv,
                            const float* __restrict__ ls, const float* __restrict__ lb,
                            const float* __restrict__ lm, const float* __restrict__ lv,
                            float* __restrict__ mulF, float* __restrict__ addF,
                            float* __restrict__ mulL, float* __restrict__ addL) {
  int c = blockIdx.x * 256 + threadIdx.x;
  if (c >= NC) return;
  float gf = 2.f / (1.f + __expf(-gF[0])) - 1.f;   // sigmoid*2-1
  float gl = 2.f / (1.f + __expf(-gL[0])) - 1.f;
  float invf = fs[c] * rsqrtf(fv[c] + 1e-5f);
  mulF[c] = gl * dwfw[c] * invf;                              // multiplies x_LFS*att
  addF[c] = (dwfb[c] - fm[c]) * invf + fb[c];
  float invl = ls[c] * rsqrtf(lv[c] + 1e-5f);
  mulL[c] = gf * dwlw[c] * invl;                              // multiplies x_FAD*att
  addL[c] = (dwlb[c] - lm[c]) * invl + lb[c];
}

// ---------- kernel 1: x fp32 [b][c][p] -> xT bf16 [b_local][p(1536)][c(768)] zero-padded ----------
// z in [0, 2*ng): first ng = FAD batches, next ng = LFS batches.
__global__ __launch_bounds__(256) void transpose_pad(const float* __restrict__ xF,
                                                     const float* __restrict__ xL,
                                                     u16* __restrict__ xTF,
                                                     u16* __restrict__ xTL,
                                                     int bbase, int ng) {
  __shared__ u16 tile[128][69];
  int z = blockIdx.z;
  int tensor = (z >= ng) ? 1 : 0;
  int bl = z - (tensor ? ng : 0);  // group-local batch
  int b = bbase + bl;              // global batch
  const float* x = tensor ? xL : xF;
  u16* xT = tensor ? xTL : xTF;
  int p0 = blockIdx.x * 64, c0 = blockIdx.y * 128;
  int t = threadIdx.x;
  // phase 1: float4 loads; 16 lanes cover 64 p, 16 c-rows per iter, 8 iters
  int pl4 = (t & 15) * 4, csub = t >> 4;
  bool fullp = (p0 + 63) < NP;
#pragma unroll
  for (int it = 0; it < 8; ++it) {
    int cl = it * 16 + csub;
    int c = c0 + cl, p = p0 + pl4;
    u16 o0v = 0, o1 = 0, o2 = 0, o3 = 0;
    if (c < NC) {
      const float* src = &x[(size_t)(b * NC + c) * NP + p];
      if (fullp) {
        float4 v = *(const float4*)src;
        o0v = f2bf(v.x); o1 = f2bf(v.y); o2 = f2bf(v.z); o3 = f2bf(v.w);
      } else {
        if (p + 0 < NP) o0v = f2bf(src[0]);
        if (p + 1 < NP) o1 = f2bf(src[1]);
        if (p + 2 < NP) o2 = f2bf(src[2]);
        if (p + 3 < NP) o3 = f2bf(src[3]);
      }
    }
    tile[cl][pl4] = o0v; tile[cl][pl4 + 1] = o1; tile[cl][pl4 + 2] = o2; tile[cl][pl4 + 3] = o3;
  }
  __syncthreads();
  // phase 2: write [p][c] with 8 consecutive c per thread (16B stores, coalesced per row)
  int j = t & 15, psub = t >> 4;   // j -> c-group of 8, psub -> p within 16
#pragma unroll
  for (int it = 0; it < 4; ++it) {
    int pl = it * 16 + psub;
    int cg = j * 8;
    int c = c0 + cg;
    u16x8 v;
#pragma unroll
    for (int k = 0; k < 8; ++k) v[k] = tile[cg + k][pl];
    *(u16x8*)&xT[(size_t)(bl * P2 + p0 + pl) * K3 + c] = v;
  }
}

// ---------- kernel 2: pad + PRE-SWIZZLE 4 weight matrices into MFMA-fragment order ----------
// Layout per combo: element idx = ((og*NKT + kt)*64 + lane)*8 + j  where
//   og in [0,48) = 16-row output group, kt in [0,24) = 32-wide k-slot, lane = MFMA lane.
//   value = W[og*16 + (lane&15)][kt*32 + (lane>>4)*8 + j]  (zero-padded).
// Each A-fragment (og,kt) is ONE fully-coalesced 1KB wave load in conv_gemm.
__global__ void pad_weights(const float* __restrict__ W0, const float* __restrict__ W1,
                            const float* __restrict__ W2, const float* __restrict__ W3,
                            u16* __restrict__ Wpad) {
  int combo = blockIdx.y;
  const float* W = combo == 0 ? W0 : combo == 1 ? W1 : combo == 2 ? W2 : W3;
  int idx = blockIdx.x * 256 + threadIdx.x;
  if (idx >= M2 * K3) return;
  int j = idx & 7;
  int l = (idx >> 3) & 63;
  int v = idx >> 9;            // og*NKT + kt
  int kt = v % NKT, og = v / NKT;
  int row = og * 16 + (l & 15);
  int col = kt * 32 + (l >> 4) * 8 + j;
  u16 val = (row < NC && col < NC) ? f2bf(W[row * NC + col]) : (u16)0;
  Wpad[(size_t)combo * (M2 * K3) + idx] = val;
}

// ---------- kernel 3: conv1x1 GEMM  Out[bl][o][p] = sum_c W[o][c]*xT[bl][p][c] + bias[o] ----------
// 2-barrier loop, BK=64 (TWO 32-wide MFMA half-steps per barrier window -> half the
// vmcnt(0) drains of BK=32). A direct-from-global in fragment order (L2-hot, in-loop
// loads -- r5's register prefetch reverted: it cost an occupancy bracket).
// LDS carries only B (double-buffered, gload_lds width-16).
// grid: (12, 12, 2*ng) = (xc: o-tile x combo-half, p-tile, bl x tensor); nwg % 8 == 0.
__global__ __launch_bounds__(256) void conv_gemm(const u16* __restrict__ Wpad,
                                                 const u16* __restrict__ xTF,
                                                 const u16* __restrict__ xTL,
                                                 const float* __restrict__ b0, const float* __restrict__ b1,
                                                 const float* __restrict__ b2, const float* __restrict__ b3,
                                                 u16* __restrict__ Qf, u16* __restrict__ Kf,
                                                 u16* __restrict__ Ql, u16* __restrict__ Kl) {
  __shared__ __align__(16) u16 B_lds[2][128 * 64];
  int t = threadIdx.x;
  int lane = t & 63, w = t >> 6;

  // XCD chunk swizzle over the flat work id (T1, bijective: nwg multiple of 8)
  unsigned int f = blockIdx.x + 12u * (blockIdx.y + 12u * blockIdx.z);
  unsigned int nwg = 144u * gridDim.z;
  unsigned int q = nwg >> 3;
  unsigned int wid = (f & 7u) * q + (f >> 3);
  unsigned int xc = wid % 12u;
  unsigned int r1 = wid / 12u;
  unsigned int pt = r1 % 12u;
  unsigned int zz = r1 / 12u;
  int bl = (int)(zz >> 1);
  int th = (int)(zz & 1u);                 // 0 = FAD (Q/K f), 1 = LFS
  int combo = th * 2 + (xc >= 6u ? 1 : 0);
  int o0 = (int)(xc % 6u) * 128;
  int p0 = (int)pt * 128;

  const u16* WbS = Wpad + (size_t)combo * (M2 * K3);
  const u16* Xb = (th == 0 ? xTF : xTL) + (size_t)bl * (P2 * K3);
  const float* bias = combo == 0 ? b0 : combo == 1 ? b1 : combo == 2 ? b2 : b3;
  u16* Out = combo == 0 ? Qf : combo == 1 ? Kf : combo == 2 ? Ql : Kl;

  // B async staging: wave w covers 32 rows x 64 c = 4 KB = 4 calls of 8 rows each.
  // lane L -> row L/8, 16B chunk L%8 (B-row = 64 c = 128 B = 8 chunks).
  const u16* Bg = Xb + (size_t)(p0 + w * 32 + (lane >> 3)) * K3 + (lane & 7) * 8;

  floatx4 acc[4][4] = {};
  int wm = w >> 1, wn = w & 1;
  int ln = lane & 15, qd = lane >> 4;
  // A fragment base for this wave: og0 = o0/16 + wm*4; fragment (og0+mt, kt) at
  //   WbS + ((og0+mt)*NKT + kt)*512 + lane*8   (u16 units; 512 u16 = 1KB per fragment)
  const u16* Afrag = WbS + (size_t)((o0 >> 4) + wm * 4) * NKT * 512 + (size_t)lane * 8;
  int rdoffB = (wn * 64 + ln) * 64 + qd * 8;   // row stride 64 u16 now

  // prologue: stage B tile 0 (c 0..63) into buffer 0
  {
    u16* Bl = &B_lds[0][w * 32 * 64];
#pragma unroll
    for (int r = 0; r < 4; ++r) async16(Bg + (size_t)r * 8 * K3, Bl + r * 8 * 64);
  }
  __syncthreads();  // vmcnt(0) drained -> buf0 ready

  int cur = 0;
  for (int kt = 0; kt < 12; ++kt) {
    if (kt + 1 < 12) {  // prefetch B tile kt+1 before compute of tile kt
      int ko = (kt + 1) * 64;
      u16* Bl = &B_lds[cur ^ 1][w * 32 * 64];
#pragma unroll
      for (int r = 0; r < 4; ++r) async16(Bg + (size_t)r * 8 * K3 + ko, Bl + r * 8 * 64);
    }
    // two 32-wide half-steps per barrier window
#pragma unroll
    for (int h = 0; h < 2; ++h) {
      int ks = kt * 2 + h;
      bf16x8 af[4], bfv[4];
#pragma unroll
      for (int mt = 0; mt < 4; ++mt)
        af[mt] = *(const bf16x8*)(Afrag + (size_t)(mt * NKT + ks) * 512);
#pragma unroll
      for (int nt = 0; nt < 4; ++nt)
        bfv[nt] = *(const bf16x8*)&B_lds[cur][rdoffB + nt * 16 * 64 + h * 32];
#pragma unroll
      for (int mt = 0; mt < 4; ++mt)
#pragma unroll
        for (int nt = 0; nt < 4; ++nt)
          acc[mt][nt] = __builtin_amdgcn_mfma_f32_16x16x32_bf16(af[mt], bfv[nt], acc[mt][nt], 0, 0, 0);
    }
    __syncthreads();  // reads of buf[cur] done everywhere; prefetch into buf[cur^1] drained
    cur ^= 1;
  }

  // epilogue: C/D layout col=lane&15 (p), row=quad*4+reg (o); add bias, store bf16
#pragma unroll
  for (int mt = 0; mt < 4; ++mt)
#pragma unroll
    for (int reg = 0; reg < 4; ++reg) {
      int o_r = o0 + wm * 64 + mt * 16 + qd * 4 + reg;
      if (o_r < NC) {
        float bv = bias[o_r];
#pragma unroll
        for (int nt = 0; nt < 4; ++nt) {
          int p_c = p0 + wn * 64 + nt * 16 + ln;
          if (p_c < NP) Out[(size_t)(bl * NC + o_r) * NP + p_c] = f2bf(acc[mt][nt][reg] + bv);
        }
      }
    }
}

// ---------- kernel 4: per-(bl,c) energy GEMM + softmax + fused output epilogue ----------
// One wave per (b_local,c). E[i,k] = sum_j qf[i,j]kf[k,j] + ql[i,j]kl[k,j]; K-dim padded
// layout [48 rows][96 cols]: cols 0..37 = FAD j, 48..85 = LFS j (pad cols zeroed).
// Rows 38..47 are left as garbage: they feed only E rows/cols that softmax+epilogue mask.
__global__ __launch_bounds__(64) void attn_final(const u16* __restrict__ Qf, const u16* __restrict__ Kf,
                                                 const u16* __restrict__ Ql, const u16* __restrict__ Kl,
                                                 const float* __restrict__ xF, const float* __restrict__ xL,
                                                 const float* __restrict__ mulF, const float* __restrict__ addF,
                                                 const float* __restrict__ mulL, const float* __restrict__ addL,
                                                 float* __restrict__ out, int bbase) {
  __shared__ __align__(16) u16 q_lds[48 * 96];
  __shared__ __align__(16) u16 k_lds[48 * 96];
  int bc = blockIdx.x;                 // bl*NC + c
  int bl = bc / NC, c = bc - bl * NC;
  int t = threadIdx.x;                 // one wave: t == lane
  int base = bc * NP;                  // group-local Q/K base
  int gbase = ((bbase + bl) * NC + c) * NP;  // global x/out base

  // zero contraction-pad cols (38..47, 86..95) for rows 0..37 (u32 = 2 cols per write)
  for (int i = t; i < 38 * 5; i += 64) {
    int r = i / 5, c2 = (i - r * 5) * 2;
    *(unsigned int*)&q_lds[r * 96 + 38 + c2] = 0;
    *(unsigned int*)&q_lds[r * 96 + 86 + c2] = 0;
    *(unsigned int*)&k_lds[r * 96 + 38 + c2] = 0;
    *(unsigned int*)&k_lds[r * 96 + 86 + c2] = 0;
  }

  // vectorized staging: 3 dwordx4 sweeps per array; scatter 8 u16 each into [48][96]
#define STAGE(SRC, DST, COL0)                                              \
  {                                                                        \
    _Pragma("unroll") for (int s = 0; s < 3; ++s) {                        \
      int e0 = (s * 64 + t) * 8;                                           \
      if (e0 < NP) {                                                       \
        u16x8 v = *(const u16x8*)(SRC + base + e0);                        \
        int r = e0 / 38, cc = e0 - r * 38;                                 \
        _Pragma("unroll") for (int j = 0; j < 8; ++j) {                    \
          if (e0 + j < NP) DST[r * 96 + (COL0) + cc] = v[j];               \
          if (++cc == 38) { cc = 0; ++r; }                                 \
        }                                                                  \
      }                                                                    \
    }                                                                      \
  }
  STAGE(Qf, q_lds, 0)
  STAGE(Ql, q_lds, 48)
  STAGE(Kf, k_lds, 0)
  STAGE(Kl, k_lds, 48)
#undef STAGE
  __syncthreads();

  int ln = t & 15, qd = t >> 4;
  floatx4 acc[3][3] = {};
#pragma unroll
  for (int ks = 0; ks < 3; ++ks) {
    bf16x8 af[3], bfv[3];
#pragma unroll
    for (int mt = 0; mt < 3; ++mt) af[mt] = *(const bf16x8*)&q_lds[(mt * 16 + ln) * 96 + ks * 32 + qd * 8];
#pragma unroll
    for (int nt = 0; nt < 3; ++nt) bfv[nt] = *(const bf16x8*)&k_lds[(nt * 16 + ln) * 96 + ks * 32 + qd * 8];
#pragma unroll
    for (int mt = 0; mt < 3; ++mt)
#pragma unroll
      for (int nt = 0; nt < 3; ++nt)
        acc[mt][nt] = __builtin_amdgcn_mfma_f32_16x16x32_bf16(af[mt], bfv[nt], acc[mt][nt], 0, 0, 0);
  }
  // softmax over k (axis -1). Row i lives in lanes sharing quad: reduce width 16.
  float rinv[3][4];
#pragma unroll
  for (int mt = 0; mt < 3; ++mt)
#pragma unroll
    for (int reg = 0; reg < 4; ++reg) {
      float m = -1e30f;
#pragma unroll
      for (int nt = 0; nt < 3; ++nt)
        if (nt * 16 + ln < HW) m = fmaxf(m, acc[mt][nt][reg]);
#pragma unroll
      for (int off = 8; off > 0; off >>= 1) m = fmaxf(m, __shfl_xor(m, off, 16));
      float s = 0.f;
#pragma unroll
      for (int nt = 0; nt < 3; ++nt) {
        float v = (nt * 16 + ln < HW) ? __expf(acc[mt][nt][reg] - m) : 0.f;
        acc[mt][nt][reg] = v;
        s += v;
      }
#pragma unroll
      for (int off = 8; off > 0; off >>= 1) s += __shfl_xor(s, off, 16);
      rinv[mt][reg] = 1.f / s;
    }

  __syncthreads();  // all q_lds fragment reads done; safe to overwrite with probs
  float* att = (float*)q_lds;  // 1444 f32 = 5776 B < 9216 B
#pragma unroll
  for (int mt = 0; mt < 3; ++mt)
#pragma unroll
    for (int reg = 0; reg < 4; ++reg) {
      int i = mt * 16 + qd * 4 + reg;
      if (i < HW) {
#pragma unroll
        for (int nt = 0; nt < 3; ++nt) {
          int k = nt * 16 + ln;
          if (k < HW) att[i * HW + k] = acc[mt][nt][reg] * rinv[mt][reg];
        }
      }
    }
  __syncthreads();

  // coalesced fused epilogue: p-contiguous float4 over both outputs
  float mf = mulF[c], adf = addF[c], ml = mulL[c], adl = addL[c];
#pragma unroll
  for (int s = 0; s < 6; ++s) {
    int p = s * 256 + t * 4;
    if (p < NP) {  // NP % 4 == 0: every in-range float4 is full
      float4 a  = *(const float4*)&att[p];
      float4 xf = *(const float4*)&xF[gbase + p];
      float4 xl = *(const float4*)&xL[gbase + p];
      float4 yf, yl;
      yf.x = fmaf(xl.x * a.x, mf, xf.x + adf); yl.x = fmaf(xf.x * a.x, ml, xl.x + adl);
      yf.y = fmaf(xl.y * a.y, mf, xf.y + adf); yl.y = fmaf(xf.y * a.y, ml, xl.y + adl);
      yf.z = fmaf(xl.z * a.z, mf, xf.z + adf); yl.z = fmaf(xf.z * a.z, ml, xl.z + adl);
      yf.w = fmaf(xl.w * a.w, mf, xf.w + adf); yl.w = fmaf(xf.w * a.w, ml, xl.w + adl);
      *(float4*)&out[gbase + p] = yf;
      *(float4*)&out[NPIX + gbase + p] = yl;
    }
  }
}

extern "C" void kernel_launch(void* const* d_in, const int* in_sizes, int n_in,
                              void* d_out, int out_size, void* d_ws, size_t ws_size,
                              hipStream_t stream) {
  (void)in_sizes; (void)n_in; (void)out_size;
  const float* xF   = (const float*)d_in[0];
  const float* xL   = (const float*)d_in[1];
  const float* Wq_f = (const float*)d_in[2];
  const float* bq_f = (const float*)d_in[3];
  const float* Wq_l = (const float*)d_in[4];
  const float* bq_l = (const float*)d_in[5];
  const float* Wk_f = (const float*)d_in[6];
  const float* bk_f = (const float*)d_in[7];
  const float* Wk_l = (const float*)d_in[8];
  const float* bk_l = (const float*)d_in[9];
  const float* gF   = (const float*)d_in[10];
  const float* gL   = (const float*)d_in[11];
  const float* dwfw = (const float*)d_in[12];
  const float* dwfb = (const float*)d_in[13];
  const float* dwlw = (const float*)d_in[14];
  const float* dwlb = (const float*)d_in[15];
  const float* fs   = (const float*)d_in[16];
  const float* fb   = (const float*)d_in[17];
  const float* fm   = (const float*)d_in[18];
  const float* fv   = (const float*)d_in[19];
  const float* ls   = (const float*)d_in[20];
  const float* lb   = (const float*)d_in[21];
  const float* lm   = (const float*)d_in[22];
  const float* lv   = (const float*)d_in[23];

  // Dynamic group size (K3=768): single pass (ng=16) needs ~215 MB of workspace;
  // ng=8 -> ~110 MB; ng=4 -> ~57 MB.
  const size_t small_bytes = 4 * (size_t)NC * sizeof(float);
  const size_t wpad_bytes  = (size_t)4 * M2 * K3 * 2;
  const size_t perb_bytes  = (size_t)2 * P2 * K3 * 2
                           + (size_t)4 * NC * NP * 2;
  int ng = 16;
  while (ng > 4 && small_bytes + wpad_bytes + (size_t)ng * perb_bytes > ws_size) ng >>= 1;

  char* ws = (char*)d_ws;
  size_t off = 0;
  float* mulF = (float*)(ws + off); off += NC * sizeof(float);
  float* addF = (float*)(ws + off); off += NC * sizeof(float);
  float* mulL = (float*)(ws + off); off += NC * sizeof(float);
  float* addL = (float*)(ws + off); off += NC * sizeof(float);
  off = (off + 15) & ~(size_t)15;
  u16* Wpad = (u16*)(ws + off); off += wpad_bytes;
  u16* xTF  = (u16*)(ws + off); off += (size_t)ng * P2 * K3 * 2;
  u16* xTL  = (u16*)(ws + off); off += (size_t)ng * P2 * K3 * 2;
  u16* Qf   = (u16*)(ws + off); off += (size_t)ng * NC * NP * 2;
  u16* Kf   = (u16*)(ws + off); off += (size_t)ng * NC * NP * 2;
  u16* Ql   = (u16*)(ws + off); off += (size_t)ng * NC * NP * 2;
  u16* Kl   = (u16*)(ws + off); off += (size_t)ng * NC * NP * 2;

  prep_params<<<dim3(3), dim3(256), 0, stream>>>(gF, gL, dwfw, dwfb, dwlw, dwlb,
                                                 fs, fb, fm, fv, ls, lb, lm, lv,
                                                 mulF, addF, mulL, addL);
  pad_weights<<<dim3((M2 * K3 + 255) / 256, 4), dim3(256), 0, stream>>>(Wq_f, Wk_f, Wq_l, Wk_l, Wpad);
  for (int g = 0; g < NB; g += ng) {
    transpose_pad<<<dim3(P2 / 64, 6, 2 * ng), dim3(256), 0, stream>>>(xF, xL, xTF, xTL, g, ng);
    conv_gemm<<<dim3(12, 12, 2 * ng), dim3(256), 0, stream>>>(Wpad, xTF, xTL,
                                                              bq_f, bk_f, bq_l, bk_l,
                                                              Qf, Kf, Ql, Kl);
    attn_final<<<dim3(ng * NC), dim3(64), 0, stream>>>(Qf, Kf, Ql, Kl, xF, xL,
                                                       mulF, addF, mulL, addL,
                                                       (float*)d_out, g);
  }
}